// Round 19
// baseline (1786.545 us; speedup 1.0000x reference)
//
#include <hip/hip_runtime.h>
#include <hip/hip_bf16.h>
#include <math.h>

// ---------------------------------------------------------------------------
// CapsuleNetwork forward.
// FAST PATH (ws >= 116,391,936 B):
//   conv1c : img -> xTh/xTl [128 b][32 cc][400 pos][8 ic] bf16 hi/lo (fused)
//   wsplit3: pcaps_w -> Wf hi/lo [qc=32][T=41][256 oc][2 h][8 ic], tap=2T+h
//   gemm11 : 576 blocks = 72 mt x 8 q. 4 waves = og(2: 128 oc, nf=4) x
//            kh(2: T halves 0-20 / 21-40). Per T: 4 A ds_reads feed 24 MFMA
//            (A-LDS traffic halved vs og4); W reads disjoint (traffic same).
//            2-deep register pipeline; kh tree-reduce via LDS epilogue.
//   squash : part(nq=8)+bias -> u (float4 accumulate)
//   uhat   : u, rw -> uh bf16 [b][o][1152][16]  (rw read ONCE)
//   routing: uh slice -> LDS, 3 dynamic-routing iters -> out
// FALLBACK: R5 fp32 direct-conv path.
// ---------------------------------------------------------------------------

typedef __attribute__((ext_vector_type(8)))  short  short8;
typedef __attribute__((ext_vector_type(8)))  ushort ushort8v;
typedef __attribute__((ext_vector_type(16))) float  f32x16;
#define MFMA32(a, b, c) __builtin_amdgcn_mfma_f32_32x32x16_bf16(a, b, c, 0, 0, 0)

__device__ __forceinline__ void split_bf16(float v, ushort& h, ushort& l) {
    __hip_bfloat16 hb = __float2bfloat16(v);
    float hf = __bfloat162float(hb);
    __hip_bfloat16 lb = __float2bfloat16(v - hf);
    h = *reinterpret_cast<ushort*>(&hb);
    l = *reinterpret_cast<ushort*>(&lb);
}

__device__ __forceinline__ void gl_lds16(const void* g, const void* lds_uniform_base) {
    __builtin_amdgcn_global_load_lds(
        (const __attribute__((address_space(1))) void*)g,
        (__attribute__((address_space(3))) void*)lds_uniform_base,
        16, 0, 0);
}

__device__ __forceinline__ int sigr(int r) { return r ^ ((r >> 3) & 7); }

// ------------------------------- conv1c ------------------------------------
__global__ __launch_bounds__(256) void conv1c_kernel(
    const float* __restrict__ img, const float* __restrict__ w,
    const float* __restrict__ bias, ushort* __restrict__ xTh, ushort* __restrict__ xTl)
{
    const int ct = blockIdx.x;   // 4
    const int b  = blockIdx.y;   // 128
    const int t  = threadIdx.x;
    __shared__ float img_s[784];
    __shared__ float w_s[64 * 81];
    __shared__ ushort xsH[32][408];
    __shared__ ushort xsL[32][408];
    for (int idx = t; idx < 784; idx += 256) img_s[idx] = img[b * 784 + idx];
    for (int idx = t; idx < 64 * 81; idx += 256) w_s[idx] = w[ct * 64 * 81 + idx];
    __syncthreads();
#pragma unroll
    for (int ph = 0; ph < 2; ++ph) {
        if (ph) __syncthreads();
        for (int task = t; task < 640; task += 256) {
            const int cl2 = task / 20;
            const int cl  = ph * 32 + cl2;
            const int oy  = task - cl2 * 20;
            float acc[20];
            const float bv = bias[ct * 64 + cl];
#pragma unroll
            for (int j = 0; j < 20; ++j) acc[j] = bv;
#pragma unroll
            for (int ky = 0; ky < 9; ++ky) {
                float rowv[28];
                const float* r = &img_s[(oy + ky) * 28];
#pragma unroll
                for (int j = 0; j < 28; ++j) rowv[j] = r[j];
#pragma unroll
                for (int kx = 0; kx < 9; ++kx) {
                    const float wv = w_s[cl * 81 + ky * 9 + kx];
#pragma unroll
                    for (int j = 0; j < 20; ++j) acc[j] += wv * rowv[j + kx];
                }
            }
#pragma unroll
            for (int j = 0; j < 20; ++j) {
                ushort hb, lb;
                split_bf16(fmaxf(acc[j], 0.f), hb, lb);
                xsH[cl2][oy * 20 + j] = hb;
                xsL[cl2][oy * 20 + j] = lb;
            }
        }
        __syncthreads();
        for (int u2 = t; u2 < 1600; u2 += 256) {
            const int c = u2 / 400;
            const int p = u2 - c * 400;
            ushort8v vh, vl;
#pragma unroll
            for (int j = 0; j < 8; ++j) {
                vh[j] = xsH[c * 8 + j][p];
                vl[j] = xsL[c * 8 + j][p];
            }
            const int cc = ct * 8 + ph * 4 + c;
            const size_t o = (((size_t)b * 32 + cc) * 400 + p) * 8;
            *(ushort8v*)(xTh + o) = vh;
            *(ushort8v*)(xTl + o) = vl;
        }
    }
}

// ------------------------------ wsplit3 ------------------------------------
__global__ __launch_bounds__(256) void wsplit3_kernel(
    const float* __restrict__ pw, ushort* __restrict__ Wfh, ushort* __restrict__ Wfl)
{
    const int oc = blockIdx.x & 255;
    const int qg = blockIdx.x >> 8;
    const int t  = threadIdx.x;
    __shared__ float buf[5184];
    const float* row = pw + (size_t)oc * 20736 + qg * 5184;
    for (int idx = t; idx < 5184; idx += 256) buf[idx] = row[idx];
    __syncthreads();
    for (int task = t; task < 656; task += 256) {
        const int qcl = task / 82;
        const int tt  = task - qcl * 82;
        const int T   = tt >> 1;
        const int hh  = tt & 1;
        const int tap = 2 * T + hh;
        const int qc  = qg * 8 + qcl;
        ushort8v h8, l8;
#pragma unroll
        for (int j = 0; j < 8; ++j) {
            const float v = (tap <= 80) ? buf[qcl * 648 + j * 81 + tap] : 0.f;
            ushort hb, lb;
            split_bf16(v, hb, lb);
            h8[j] = hb; l8[j] = lb;
        }
        const size_t rec = (((size_t)(qc * 41 + T) * 256 + oc) * 2 + hh) * 8;
        *(ushort8v*)(Wfh + rec) = h8;
        *(ushort8v*)(Wfl + rec) = l8;
    }
}

// ------------------------------- gemm11 ------------------------------------
__global__ __launch_bounds__(256, 2) void gemm11_kernel(
    const ushort* __restrict__ xTh, const ushort* __restrict__ xTl,
    const ushort* __restrict__ Wfh, const ushort* __restrict__ Wfl,
    float* __restrict__ part)
{
    const int bid = blockIdx.x;          // 576
    const int q = bid & 7, mt = bid >> 3;
    const int t = threadIdx.x;           // 0..255
    const int w = t >> 6, lane = t & 63;
    const int ln = lane & 31, h = lane >> 5;
    const int og = w & 1, kh = w >> 1;   // og: 128-oc half; kh: T half

    __shared__ ushort As[20480];         // 40 KB A tile (hi [0,1200), lo base 1280)

    const int m_base = mt * 64;
    const int bmin = m_base / 36;

    uint soff[5];
#pragma unroll
    for (int r = 0; r < 5; ++r) {
        int j = t + r * 256;
        if (j >= 1200) j = 0;
        const int rbj = j / 400;
        const int gp  = sigr(j) - rbj * 400;
        soff[r] = (uint)((bmin + rbj) * 204800 + q * 25600 + gp * 16);
    }

    int pb0, pb1;
    {
        int m = m_base + ln;
        int b = m / 36, pos = m - b * 36;
        pb0 = (b - bmin) * 400 + (pos / 6) * 40 + (pos % 6) * 2;
        m += 32;
        b = m / 36; pos = m - b * 36;
        pb1 = (b - bmin) * 400 + (pos / 6) * 40 + (pos % 6) * 2;
    }

    const int T0 = kh ? 21 : 0;
    const int T1 = kh ? 41 : 21;
    const uint wlane = (uint)((og * 128 + ln) * 16 + h * 8);

    f32x16 c00, c01, c02, c03, c10, c11, c12, c13;
#pragma unroll
    for (int i = 0; i < 16; ++i) {
        c00[i] = 0.f; c01[i] = 0.f; c02[i] = 0.f; c03[i] = 0.f;
        c10[i] = 0.f; c11[i] = 0.f; c12[i] = 0.f; c13[i] = 0.f;
    }

#define G11_LOAD(T_, S)                                                        \
    {                                                                          \
        const int tap_ = 2 * (T_) + h;                                         \
        const int ky_  = (tap_ * 57) >> 9;                                     \
        const int off_ = ky_ * 20 + tap_ - 9 * ky_;                            \
        const int s0_ = sigr(pb0 + off_);                                      \
        const int s1_ = sigr(pb1 + off_);                                      \
        S##a0h = *(const short8*)(As + s0_ * 8);                               \
        S##a0l = *(const short8*)(As + (1280 + s0_) * 8);                      \
        S##a1h = *(const short8*)(As + s1_ * 8);                               \
        S##a1l = *(const short8*)(As + (1280 + s1_) * 8);                      \
        const ushort* wh_ = wbh + (size_t)(T_) * 4096;                         \
        const ushort* wl_ = wbl + (size_t)(T_) * 4096;                         \
        S##w0h = *(const short8*)(wh_);          S##w1h = *(const short8*)(wh_ + 512);  \
        S##w2h = *(const short8*)(wh_ + 1024);   S##w3h = *(const short8*)(wh_ + 1536); \
        S##w0l = *(const short8*)(wl_);          S##w1l = *(const short8*)(wl_ + 512);  \
        S##w2l = *(const short8*)(wl_ + 1024);   S##w3l = *(const short8*)(wl_ + 1536); \
    }

#define G11_MFMA(S)                                                            \
    {                                                                          \
        c00 = MFMA32(S##a0h, S##w0h, c00); c00 = MFMA32(S##a0l, S##w0h, c00);  \
        c00 = MFMA32(S##a0h, S##w0l, c00);                                     \
        c10 = MFMA32(S##a1h, S##w0h, c10); c10 = MFMA32(S##a1l, S##w0h, c10);  \
        c10 = MFMA32(S##a1h, S##w0l, c10);                                     \
        c01 = MFMA32(S##a0h, S##w1h, c01); c01 = MFMA32(S##a0l, S##w1h, c01);  \
        c01 = MFMA32(S##a0h, S##w1l, c01);                                     \
        c11 = MFMA32(S##a1h, S##w1h, c11); c11 = MFMA32(S##a1l, S##w1h, c11);  \
        c11 = MFMA32(S##a1h, S##w1l, c11);                                     \
        c02 = MFMA32(S##a0h, S##w2h, c02); c02 = MFMA32(S##a0l, S##w2h, c02);  \
        c02 = MFMA32(S##a0h, S##w2l, c02);                                     \
        c12 = MFMA32(S##a1h, S##w2h, c12); c12 = MFMA32(S##a1l, S##w2h, c12);  \
        c12 = MFMA32(S##a1h, S##w2l, c12);                                     \
        c03 = MFMA32(S##a0h, S##w3h, c03); c03 = MFMA32(S##a0l, S##w3h, c03);  \
        c03 = MFMA32(S##a0h, S##w3l, c03);                                     \
        c13 = MFMA32(S##a1h, S##w3h, c13); c13 = MFMA32(S##a1l, S##w3h, c13);  \
        c13 = MFMA32(S##a1h, S##w3l, c13);                                     \
    }

#define G11_STAGE(c_)                                                          \
    {                                                                          \
        const uint cc = (uint)(c_) * 6400u;                                    \
        _Pragma("unroll")                                                      \
        for (int r = 0; r < 5; ++r) {                                          \
            if (r < 4 || t < 176) {                                            \
                gl_lds16((const char*)xTh + soff[r] + cc,                      \
                         (char*)As + (r * 256 + w * 64) * 16);                 \
                gl_lds16((const char*)xTl + soff[r] + cc,                      \
                         (char*)As + 20480 + (r * 256 + w * 64) * 16);         \
            }                                                                  \
        }                                                                      \
    }

    for (int c = 0; c < 4; ++c) {
        if (c > 0) __syncthreads();
        G11_STAGE(c);
        __syncthreads();                // implicit vmcnt(0): stage visible

        const ushort* wbh = Wfh + (size_t)(q * 4 + c) * 41 * 4096 + wlane;
        const ushort* wbl = Wfl + (size_t)(q * 4 + c) * 41 * 4096 + wlane;

        short8 A_a0h, A_a0l, A_a1h, A_a1l, A_w0h, A_w1h, A_w2h, A_w3h,
               A_w0l, A_w1l, A_w2l, A_w3l;
        short8 B_a0h, B_a0l, B_a1h, B_a1l, B_w0h, B_w1h, B_w2h, B_w3h,
               B_w0l, B_w1l, B_w2l, B_w3l;

        G11_LOAD(T0, A_)
        G11_LOAD(T0 + 1, B_)

        int TT = T0;
#pragma unroll 1
        for (; TT + 2 < T1; TT += 2) {
            G11_MFMA(A_)
            {
                const int Tn = (TT + 2 < T1) ? TT + 2 : T1 - 1;
                G11_LOAD(Tn, A_)
            }
            G11_MFMA(B_)
            {
                const int Tn = (TT + 3 < T1) ? TT + 3 : T1 - 1;
                G11_LOAD(Tn, B_)
            }
        }
        G11_MFMA(A_)                    // T = TT
        if (TT + 1 < T1) { G11_MFMA(B_) }
    }
#undef G11_STAGE
#undef G11_MFMA
#undef G11_LOAD

    // ---- kh tree reduce via LDS (2 passes of 4 acc vars each) ----
    float4* red = (float4*)As;           // 2560 float4 capacity; use 2048
    const int cidx = og * 64 + lane;     // 0..127

#define G11_RED(V0, V1, V2, V3)                                                \
    __syncthreads();                                                           \
    if (kh == 1) {                                                             \
        _Pragma("unroll") for (int e = 0; e < 4; ++e) {                        \
            red[(0 * 4 + e) * 128 + cidx] = make_float4(V0[e*4], V0[e*4+1], V0[e*4+2], V0[e*4+3]); \
            red[(1 * 4 + e) * 128 + cidx] = make_float4(V1[e*4], V1[e*4+1], V1[e*4+2], V1[e*4+3]); \
            red[(2 * 4 + e) * 128 + cidx] = make_float4(V2[e*4], V2[e*4+1], V2[e*4+2], V2[e*4+3]); \
            red[(3 * 4 + e) * 128 + cidx] = make_float4(V3[e*4], V3[e*4+1], V3[e*4+2], V3[e*4+3]); \
        }                                                                      \
    }                                                                          \
    __syncthreads();                                                           \
    if (kh == 0) {                                                             \
        _Pragma("unroll") for (int e = 0; e < 4; ++e) {                        \
            float4 v;                                                          \
            v = red[(0 * 4 + e) * 128 + cidx];                                 \
            V0[e*4] += v.x; V0[e*4+1] += v.y; V0[e*4+2] += v.z; V0[e*4+3] += v.w; \
            v = red[(1 * 4 + e) * 128 + cidx];                                 \
            V1[e*4] += v.x; V1[e*4+1] += v.y; V1[e*4+2] += v.z; V1[e*4+3] += v.w; \
            v = red[(2 * 4 + e) * 128 + cidx];                                 \
            V2[e*4] += v.x; V2[e*4+1] += v.y; V2[e*4+2] += v.z; V2[e*4+3] += v.w; \
            v = red[(3 * 4 + e) * 128 + cidx];                                 \
            V3[e*4] += v.x; V3[e*4+1] += v.y; V3[e*4+2] += v.z; V3[e*4+3] += v.w; \
        }                                                                      \
    }

    G11_RED(c00, c01, c02, c03)
    G11_RED(c10, c11, c12, c13)
#undef G11_RED

    if (kh == 0) {
        // epilogue: C[m][oc] -> part[q][b][cap][pos][d]
        float* pq = part + (size_t)q * 1179648;
#pragma unroll
        for (int mf = 0; mf < 2; ++mf) {
#pragma unroll
            for (int nf = 0; nf < 4; ++nf) {
                const f32x16 a = (mf == 0)
                    ? (nf == 0 ? c00 : nf == 1 ? c01 : nf == 2 ? c02 : c03)
                    : (nf == 0 ? c10 : nf == 1 ? c11 : nf == 2 ? c12 : c13);
                const int oc = og * 128 + nf * 32 + ln;
                float* pb = pq + (oc >> 3) * 288 + (oc & 7);
#pragma unroll
                for (int r = 0; r < 16; ++r) {
                    const int m = m_base + mf * 32 + (r & 3) + 8 * (r >> 2) + 4 * h;
                    const int b = m / 36;
                    const int pos = m - b * 36;
                    pb[(size_t)b * 9216 + pos * 8] = a[r];
                }
            }
        }
    }
}

// ------------------------------- squash ------------------------------------
__global__ __launch_bounds__(256) void squash_kernel(
    const float* __restrict__ part, const float* __restrict__ bias,
    float* __restrict__ u, int nq)
{
    const int idx = blockIdx.x * 256 + threadIdx.x;
    if (idx >= 128 * 1152) return;
    const int i   = idx % 1152;
    const int cap = i / 36;
    float4 s0, s1;
    {
        const float* bv = bias + cap * 8;
        s0 = make_float4(bv[0], bv[1], bv[2], bv[3]);
        s1 = make_float4(bv[4], bv[5], bv[6], bv[7]);
    }
    for (int qq = 0; qq < nq; ++qq) {
        const float4* p = (const float4*)(part + (size_t)qq * 1179648 + (size_t)idx * 8);
        const float4 a = p[0], b4 = p[1];
        s0.x += a.x; s0.y += a.y; s0.z += a.z; s0.w += a.w;
        s1.x += b4.x; s1.y += b4.y; s1.z += b4.z; s1.w += b4.w;
    }
    const float n2 = s0.x*s0.x + s0.y*s0.y + s0.z*s0.z + s0.w*s0.w
                   + s1.x*s1.x + s1.y*s1.y + s1.z*s1.z + s1.w*s1.w;
    const float sc = sqrtf(n2) / (1.f + n2);
    *(float4*)(u + (size_t)idx * 8)     = make_float4(s0.x*sc, s0.y*sc, s0.z*sc, s0.w*sc);
    *(float4*)(u + (size_t)idx * 8 + 4) = make_float4(s1.x*sc, s1.y*sc, s1.z*sc, s1.w*sc);
}

// ------------------------------- uhat --------------------------------------
__device__ __forceinline__ float4 uhat4(const float* __restrict__ urow,
                                        const float* __restrict__ wrow)
{
    float ur[8];
    const float4 u0 = *(const float4*)urow;
    const float4 u1 = *(const float4*)(urow + 4);
    ur[0] = u0.x; ur[1] = u0.y; ur[2] = u0.z; ur[3] = u0.w;
    ur[4] = u1.x; ur[5] = u1.y; ur[6] = u1.z; ur[7] = u1.w;
    float4 uh = make_float4(0.f, 0.f, 0.f, 0.f);
#pragma unroll
    for (int c = 0; c < 8; ++c) {
        const float4 wv = *(const float4*)(wrow + c * 16);
        uh.x += ur[c] * wv.x; uh.y += ur[c] * wv.y;
        uh.z += ur[c] * wv.z; uh.w += ur[c] * wv.w;
    }
    return uh;
}

__global__ __launch_bounds__(256) void uhat_kernel(
    const float* __restrict__ u, const float* __restrict__ rw,
    ushort* __restrict__ uh)
{
    const int i0 = blockIdx.x * 16;
    const int o  = blockIdx.y;
    const int t  = threadIdx.x;
    __shared__ float rs[2048];
    const float* rsl = rw + ((size_t)o * 1152 + i0) * 128;
    for (int idx = t; idx < 2048; idx += 256) rs[idx] = rsl[idx];
    __syncthreads();
    const int dq = t & 3, il = (t >> 2) & 15, b0 = t >> 6;
    for (int b = b0; b < 128; b += 4) {
        const float4 v = uhat4(u + ((size_t)b * 1152 + i0 + il) * 8,
                               &rs[il * 128 + dq * 4]);
        __hip_bfloat16 q0 = __float2bfloat16(v.x);
        __hip_bfloat16 q1 = __float2bfloat16(v.y);
        __hip_bfloat16 q2 = __float2bfloat16(v.z);
        __hip_bfloat16 q3 = __float2bfloat16(v.w);
        ushort4 hb;
        hb.x = *(ushort*)&q0; hb.y = *(ushort*)&q1;
        hb.z = *(ushort*)&q2; hb.w = *(ushort*)&q3;
        *(ushort4*)(uh + (((size_t)b * 10 + o) * 1152 + i0 + il) * 16 + dq * 4) = hb;
    }
}

// ------------------------------- routing v3 --------------------------------
__device__ __forceinline__ float4 uh_from_lds(const ushort* uhs, int i, int d4)
{
    const uint2 rv = *(const uint2*)(uhs + i * 16 + d4);
    float4 r;
    r.x = __uint_as_float((rv.x & 0xffffu) << 16);
    r.y = __uint_as_float((rv.x >> 16) << 16);
    r.z = __uint_as_float((rv.y & 0xffffu) << 16);
    r.w = __uint_as_float((rv.y >> 16) << 16);
    return r;
}

__global__ __launch_bounds__(256) void routing_kernel(
    const ushort* __restrict__ uh_g, float* __restrict__ out)
{
    const int b = blockIdx.x;
    const int o = blockIdx.y;
    const int t = threadIdx.x;
    __shared__ ushort uh_s[1152 * 16];
    __shared__ float logits[1152];
    __shared__ float ebuf[1152];
    __shared__ float psum[64][17];
    __shared__ float red[8];
    __shared__ float v_s[16];
    const ushort8v* src = (const ushort8v*)(uh_g + ((size_t)b * 10 + o) * 18432);
    for (int idx = t; idx < 2304; idx += 256) ((ushort8v*)uh_s)[idx] = src[idx];
    for (int i = t; i < 1152; i += 256) logits[i] = 0.f;
    __syncthreads();
    const int dq = t & 3;
    const int ig = t >> 2;
    const int d4 = dq * 4;
    for (int iter = 1; iter <= 3; ++iter) {
        float lmax = -3.0e38f;
        for (int i = t; i < 1152; i += 256) lmax = fmaxf(lmax, logits[i]);
#pragma unroll
        for (int off = 32; off; off >>= 1) lmax = fmaxf(lmax, __shfl_xor(lmax, off, 64));
        if ((t & 63) == 0) red[t >> 6] = lmax;
        __syncthreads();
        const float m = fmaxf(fmaxf(red[0], red[1]), fmaxf(red[2], red[3]));
        float ls = 0.f;
        for (int i = t; i < 1152; i += 256) {
            const float e = expf(logits[i] - m);
            ebuf[i] = e;
            ls += e;
        }
#pragma unroll
        for (int off = 32; off; off >>= 1) ls += __shfl_xor(ls, off, 64);
        if ((t & 63) == 0) red[4 + (t >> 6)] = ls;
        __syncthreads();
        const float sumE = red[4] + red[5] + red[6] + red[7];
        float4 ps = make_float4(0.f, 0.f, 0.f, 0.f);
        for (int i = ig; i < 1152; i += 64) {
            const float4 uhv = uh_from_lds(uh_s, i, d4);
            const float e = ebuf[i];
            ps.x += e * uhv.x; ps.y += e * uhv.y; ps.z += e * uhv.z; ps.w += e * uhv.w;
        }
        psum[ig][d4 + 0] = ps.x; psum[ig][d4 + 1] = ps.y;
        psum[ig][d4 + 2] = ps.z; psum[ig][d4 + 3] = ps.w;
        __syncthreads();
        if (t < 16) {
            float s = 0.f;
            for (int g = 0; g < 64; ++g) s += psum[g][t];
            s /= sumE;
            float qn = s * s;
            qn += __shfl_xor(qn, 1, 16); qn += __shfl_xor(qn, 2, 16);
            qn += __shfl_xor(qn, 4, 16); qn += __shfl_xor(qn, 8, 16);
            v_s[t] = s * sqrtf(qn) / (1.f + qn);
        }
        __syncthreads();
        if (iter < 3) {
            const float v0 = v_s[d4 + 0], v1 = v_s[d4 + 1];
            const float v2 = v_s[d4 + 2], v3 = v_s[d4 + 3];
            for (int i = ig; i < 1152; i += 64) {
                const float4 uhv = uh_from_lds(uh_s, i, d4);
                float pr = uhv.x * v0 + uhv.y * v1 + uhv.z * v2 + uhv.w * v3;
                pr += __shfl_xor(pr, 1, 64);
                pr += __shfl_xor(pr, 2, 64);
                if (dq == 0) logits[i] += pr;
            }
            __syncthreads();
        }
    }
    if (t < 16) out[((size_t)b * 10 + o) * 16 + t] = v_s[t];
}

// ===================== FALLBACK (R5 fp32 direct conv) ======================
#define WSL4 1344

__global__ __launch_bounds__(256) void conv1_kernel(
    const float* __restrict__ img, const float* __restrict__ w,
    const float* __restrict__ bias, float* __restrict__ x)
{
    const int ct = blockIdx.x;
    const int b  = blockIdx.y;
    const int t  = threadIdx.x;
    __shared__ float img_s[784];
    __shared__ float w_s[64 * 81];
    for (int idx = t; idx < 784; idx += 256) img_s[idx] = img[b * 784 + idx];
    for (int idx = t; idx < 64 * 81; idx += 256) w_s[idx] = w[ct * 64 * 81 + idx];
    __syncthreads();
    for (int task = t; task < 1280; task += 256) {
        const int cl = task / 20;
        const int oy = task - cl * 20;
        float acc[20];
        const float bv = bias[ct * 64 + cl];
#pragma unroll
        for (int j = 0; j < 20; ++j) acc[j] = bv;
#pragma unroll
        for (int ky = 0; ky < 9; ++ky) {
            float rowv[28];
            const float* r = &img_s[(oy + ky) * 28];
#pragma unroll
            for (int j = 0; j < 28; ++j) rowv[j] = r[j];
#pragma unroll
            for (int kx = 0; kx < 9; ++kx) {
                const float wv = w_s[cl * 81 + ky * 9 + kx];
#pragma unroll
                for (int j = 0; j < 20; ++j) acc[j] += wv * rowv[j + kx];
            }
        }
        float* xp = x + (((size_t)b * 256 + ct * 64 + cl) * 400) + oy * 20;
#pragma unroll
        for (int j = 0; j < 20; ++j) xp[j] = fmaxf(acc[j], 0.f);
    }
}

__global__ __launch_bounds__(256) void wtrans_kernel(
    const float* __restrict__ w, float* __restrict__ wT)
{
    const int idx = blockIdx.x * 256 + threadIdx.x;
    if (idx >= 4 * 256 * 81 * 16) return;
    const int c      = idx & 15;
    const int k      = (idx >> 4) % 81;
    const int ic     = ((idx >> 4) / 81) % 256;
    const int octile = idx / (16 * 81 * 256);
    const int ocb    = octile * 64 + c * 4;
    float4 v;
    v.x = w[((size_t)(ocb + 0) * 256 + ic) * 81 + k];
    v.y = w[((size_t)(ocb + 1) * 256 + ic) * 81 + k];
    v.z = w[((size_t)(ocb + 2) * 256 + ic) * 81 + k];
    v.w = w[((size_t)(ocb + 3) * 256 + ic) * 81 + k];
    ((float4*)wT)[((size_t)octile * 256 + ic) * WSL4 + k * 16 + c] = v;
}

__global__ __launch_bounds__(384) void pcaps_kernel(
    const float* __restrict__ x, const float* __restrict__ wT,
    float* __restrict__ part)
{
    const int btile  = blockIdx.x;
    const int octile = blockIdx.y;
    const int ict    = blockIdx.z;
    const int t    = threadIdx.x;
    const int wave = t >> 6;
    const int lane = t & 63;
    __shared__ float4 w_s[2][WSL4];
    __shared__ float4 x_s[2][448];
    const int oc4  = (t & 15) * 4;
    const int slot = t >> 4;
    const int bb   = slot / 6;
    const int oy   = slot - 6 * bb;
    const int b0   = btile * 4;
    float acc[6][4];
#pragma unroll
    for (int p = 0; p < 6; ++p) {
        acc[p][0] = 0.f; acc[p][1] = 0.f; acc[p][2] = 0.f; acc[p][3] = 0.f;
    }
    const float*  xg   = x + (size_t)b0 * 102400 + (size_t)ict * 25600;
    const float4* wsrc = (const float4*)wT + ((size_t)octile * 256 + ict * 64) * WSL4;
#define PCAPS_STAGE(bf_, ic_)                                                  \
    {                                                                          \
        const float4* gsl = wsrc + (size_t)(ic_) * WSL4;                       \
        for (int ch = wave; ch < 21; ch += 6)                                  \
            gl_lds16(gsl + ch * 64 + lane, &w_s[bf_][ch * 64]);                \
        for (int ch = wave; ch < 7; ch += 6) {                                 \
            int idx = ch * 64 + lane;                                          \
            if (idx >= 400) idx = 0;                                           \
            const int xbb = idx / 100;                                         \
            const int off = idx - xbb * 100;                                   \
            const float* g = xg + (size_t)xbb * 102400 + (ic_) * 400 + off * 4;\
            gl_lds16(g, &x_s[bf_][ch * 64]);                                   \
        }                                                                      \
    }
    PCAPS_STAGE(0, 0);
    __syncthreads();
    int buf = 0;
    for (int ic = 0; ic < 64; ++ic) {
        if (ic < 63) PCAPS_STAGE(buf ^ 1, ic + 1);
        const float* xrow = (const float*)x_s[buf] + bb * 400;
        const float* wrow = (const float*)w_s[buf];
#pragma unroll
        for (int ky = 0; ky < 9; ++ky) {
            float rowv[20];
            const float4* xr = (const float4*)&xrow[(2 * oy + ky) * 20];
#pragma unroll
            for (int j = 0; j < 5; ++j) ((float4*)rowv)[j] = xr[j];
#pragma unroll
            for (int kx = 0; kx < 9; ++kx) {
                const float4 wv = *(const float4*)&wrow[(ky * 9 + kx) * 64 + oc4];
#pragma unroll
                for (int p = 0; p < 6; ++p) {
                    const float xv = rowv[2 * p + kx];
                    acc[p][0] += xv * wv.x; acc[p][1] += xv * wv.y;
                    acc[p][2] += xv * wv.z; acc[p][3] += xv * wv.w;
                }
            }
        }
        __syncthreads();
        buf ^= 1;
    }
#undef PCAPS_STAGE
    float* pb = part + ((size_t)ict * 128 + (b0 + bb)) * 9216;
    const int oc0 = octile * 64 + oc4;
    const int cap = oc0 >> 3;
    const int d0  = oc0 & 7;
#pragma unroll
    for (int p = 0; p < 6; ++p) {
        const int pos = oy * 6 + p;
        *(float4*)&pb[((size_t)cap * 36 + pos) * 8 + d0] =
            make_float4(acc[p][0], acc[p][1], acc[p][2], acc[p][3]);
    }
}

__global__ __launch_bounds__(256) void squash_fb_kernel(
    const float* __restrict__ part, const float* __restrict__ bias,
    float* __restrict__ u, int nq)
{
    const int idx = blockIdx.x * 256 + threadIdx.x;
    if (idx >= 128 * 1152) return;
    const int i   = idx % 1152;
    const int cap = i / 36;
    float v[8];
    float n2 = 0.f;
#pragma unroll
    for (int c = 0; c < 8; ++c) {
        float s = bias[cap * 8 + c];
        for (int qq = 0; qq < nq; ++qq) s += part[(size_t)qq * 1179648 + (size_t)idx * 8 + c];
        v[c] = s;
        n2 += s * s;
    }
    const float sc = sqrtf(n2) / (1.f + n2);
#pragma unroll
    for (int c = 0; c < 8; ++c) u[(size_t)idx * 8 + c] = v[c] * sc;
}

__global__ __launch_bounds__(256) void routing_fb_kernel(
    const float* __restrict__ u, const float* __restrict__ rw,
    float* __restrict__ out)
{
    const int b = blockIdx.x;
    const int o = blockIdx.y;
    const int t = threadIdx.x;
    __shared__ ushort uh_s[1152 * 16];
    __shared__ float logits[1152];
    __shared__ float ebuf[1152];
    __shared__ float psum[64][17];
    __shared__ float red[8];
    __shared__ float v_s[16];
    const float* ub = u + (size_t)b * 9216;
    const float* wo = rw + (size_t)o * 147456;
    for (int i = t; i < 1152; i += 256) logits[i] = 0.f;
    __syncthreads();
    const int dq = t & 3;
    const int ig = t >> 2;
    const int d4 = dq * 4;
    for (int iter = 1; iter <= 3; ++iter) {
        float lmax = -3.0e38f;
        for (int i = t; i < 1152; i += 256) lmax = fmaxf(lmax, logits[i]);
#pragma unroll
        for (int off = 32; off; off >>= 1) lmax = fmaxf(lmax, __shfl_xor(lmax, off, 64));
        if ((t & 63) == 0) red[t >> 6] = lmax;
        __syncthreads();
        const float m = fmaxf(fmaxf(red[0], red[1]), fmaxf(red[2], red[3]));
        float ls = 0.f;
        for (int i = t; i < 1152; i += 256) {
            const float e = expf(logits[i] - m);
            ebuf[i] = e;
            ls += e;
        }
#pragma unroll
        for (int off = 32; off; off >>= 1) ls += __shfl_xor(ls, off, 64);
        if ((t & 63) == 0) red[4 + (t >> 6)] = ls;
        __syncthreads();
        const float sumE = red[4] + red[5] + red[6] + red[7];
        float4 ps = make_float4(0.f, 0.f, 0.f, 0.f);
        if (iter == 1) {
            for (int i = ig; i < 1152; i += 64) {
                const float4 uhv = uhat4(ub + i * 8, wo + (size_t)i * 128 + d4);
                __hip_bfloat16 q0 = __float2bfloat16(uhv.x);
                __hip_bfloat16 q1 = __float2bfloat16(uhv.y);
                __hip_bfloat16 q2 = __float2bfloat16(uhv.z);
                __hip_bfloat16 q3 = __float2bfloat16(uhv.w);
                ushort4 hb;
                hb.x = *(ushort*)&q0; hb.y = *(ushort*)&q1;
                hb.z = *(ushort*)&q2; hb.w = *(ushort*)&q3;
                *(ushort4*)(uh_s + i * 16 + d4) = hb;
                const float e = ebuf[i];
                ps.x += e * uhv.x; ps.y += e * uhv.y; ps.z += e * uhv.z; ps.w += e * uhv.w;
            }
        } else {
            for (int i = ig; i < 1152; i += 64) {
                const float4 uhv = uh_from_lds(uh_s, i, d4);
                const float e = ebuf[i];
                ps.x += e * uhv.x; ps.y += e * uhv.y; ps.z += e * uhv.z; ps.w += e * uhv.w;
            }
        }
        psum[ig][d4 + 0] = ps.x; psum[ig][d4 + 1] = ps.y;
        psum[ig][d4 + 2] = ps.z; psum[ig][d4 + 3] = ps.w;
        __syncthreads();
        if (t < 16) {
            float s = 0.f;
            for (int g = 0; g < 64; ++g) s += psum[g][t];
            s /= sumE;
            float qn = s * s;
            qn += __shfl_xor(qn, 1, 16); qn += __shfl_xor(qn, 2, 16);
            qn += __shfl_xor(qn, 4, 16); qn += __shfl_xor(qn, 8, 16);
            v_s[t] = s * sqrtf(qn) / (1.f + qn);
        }
        __syncthreads();
        if (iter < 3) {
            const float v0 = v_s[d4 + 0], v1 = v_s[d4 + 1];
            const float v2 = v_s[d4 + 2], v3 = v_s[d4 + 3];
            for (int i = ig; i < 1152; i += 64) {
                const float4 uhv = uh_from_lds(uh_s, i, d4);
                float pr = uhv.x * v0 + uhv.y * v1 + uhv.z * v2 + uhv.w * v3;
                pr += __shfl_xor(pr, 1, 64);
                pr += __shfl_xor(pr, 2, 64);
                if (dq == 0) logits[i] += pr;
            }
            __syncthreads();
        }
    }
    if (t < 16) out[((size_t)b * 10 + o) * 16 + t] = v_s[t];
}

// ------------------------------- launcher ----------------------------------
extern "C" void kernel_launch(void* const* d_in, const int* in_sizes, int n_in,
                              void* d_out, int out_size, void* d_ws, size_t ws_size,
                              hipStream_t stream)
{
    const float* img = (const float*)d_in[0];
    const float* c1w = (const float*)d_in[1];
    const float* c1b = (const float*)d_in[2];
    const float* pw  = (const float*)d_in[3];
    const float* pb  = (const float*)d_in[4];
    const float* rw  = (const float*)d_in[5];
    float* out = (float*)d_out;
    char* ws = (char*)d_ws;

    if (ws_size >= 116391936ULL) {
        // fast path (116,391,936 B)
        ushort* xTh  = (ushort*)(ws);                  // dead after gemm11
        ushort* xTl  = (ushort*)(ws + 26214400);       // dead after gemm11
        ushort* uh   = (ushort*)(ws);                  // aliases dead xT
        ushort* Wfh  = (ushort*)(ws + 52428800);
        ushort* Wfl  = (ushort*)(ws + 63176704);
        float*  part = (float*)(ws + 73924608);
        float*  u    = (float*)(ws + 111673344);
        hipLaunchKernelGGL(conv1c_kernel, dim3(4, 128), dim3(256), 0, stream, img, c1w, c1b, xTh, xTl);
        hipLaunchKernelGGL(wsplit3_kernel, dim3(1024), dim3(256), 0, stream, pw, Wfh, Wfl);
        hipLaunchKernelGGL(gemm11_kernel, dim3(576), dim3(256), 0, stream, xTh, xTl, Wfh, Wfl, part);
        hipLaunchKernelGGL(squash_kernel, dim3(576), dim3(256), 0, stream, part, pb, u, 8);
        hipLaunchKernelGGL(uhat_kernel, dim3(72, 10), dim3(256), 0, stream, u, rw, uh);
        hipLaunchKernelGGL(routing_kernel, dim3(128, 10), dim3(256), 0, stream, uh, out);
    } else {
        // fallback: R5 fp32 direct conv (97.9 MB, proven)
        float* x    = (float*)(ws);
        float* part = (float*)(ws + 52428800);
        float* u    = (float*)(ws + 52428800 + 18874368);
        float* wT   = (float*)(ws + 52428800 + 18874368 + 4718592);
        hipLaunchKernelGGL(wtrans_kernel, dim3((4 * 256 * 81 * 16 + 255) / 256), dim3(256), 0, stream, pw, wT);
        hipLaunchKernelGGL(conv1_kernel, dim3(4, 128), dim3(256), 0, stream, img, c1w, c1b, x);
        hipLaunchKernelGGL(pcaps_kernel, dim3(32, 4, 4), dim3(384), 0, stream, x, wT, part);
        hipLaunchKernelGGL(squash_fb_kernel, dim3(576), dim3(256), 0, stream, part, pb, u, 4);
        hipLaunchKernelGGL(routing_fb_kernel, dim3(128, 10), dim3(256), 0, stream, u, rw, out);
    }
}

// Round 20
// 274.718 us; speedup vs baseline: 6.5032x; 6.5032x over previous
//
#include <hip/hip_runtime.h>
#include <hip/hip_bf16.h>
#include <math.h>

// ---------------------------------------------------------------------------
// CapsuleNetwork forward.  (R20 = revert to proven R18 configuration)
// FAST PATH (ws >= 116,391,936 B):
//   conv1c : img -> xTh/xTl [128 b][32 cc][400 pos][8 ic] bf16 hi/lo (fused)
//   wsplit3: pcaps_w -> Wf hi/lo [qc=32][T=41][256 oc][2 h][8 ic], tap=2T+h
//   gemm10 : 576 blocks = 72 mt x 8 q, 4 waves (64 oc each), A staged per
//            icchunk (sigma swizzle), 2-deep register pipeline, 12 MFMA/T.
//   squash : part(nq=8)+bias -> u (float4 accumulate)
//   uhat   : u, rw -> uh bf16 [b][o][1152][16]  (rw read ONCE)
//   routing: uh slice -> LDS, 3 dynamic-routing iters -> out
// FALLBACK: R5 fp32 direct-conv path.
// ---------------------------------------------------------------------------

typedef __attribute__((ext_vector_type(8)))  short  short8;
typedef __attribute__((ext_vector_type(8)))  ushort ushort8v;
typedef __attribute__((ext_vector_type(16))) float  f32x16;
#define MFMA32(a, b, c) __builtin_amdgcn_mfma_f32_32x32x16_bf16(a, b, c, 0, 0, 0)

__device__ __forceinline__ void split_bf16(float v, ushort& h, ushort& l) {
    __hip_bfloat16 hb = __float2bfloat16(v);
    float hf = __bfloat162float(hb);
    __hip_bfloat16 lb = __float2bfloat16(v - hf);
    h = *reinterpret_cast<ushort*>(&hb);
    l = *reinterpret_cast<ushort*>(&lb);
}

__device__ __forceinline__ void gl_lds16(const void* g, const void* lds_uniform_base) {
    __builtin_amdgcn_global_load_lds(
        (const __attribute__((address_space(1))) void*)g,
        (__attribute__((address_space(3))) void*)lds_uniform_base,
        16, 0, 0);
}

__device__ __forceinline__ int sigr(int r) { return r ^ ((r >> 3) & 7); }

// ------------------------------- conv1c ------------------------------------
__global__ __launch_bounds__(256) void conv1c_kernel(
    const float* __restrict__ img, const float* __restrict__ w,
    const float* __restrict__ bias, ushort* __restrict__ xTh, ushort* __restrict__ xTl)
{
    const int ct = blockIdx.x;   // 4
    const int b  = blockIdx.y;   // 128
    const int t  = threadIdx.x;
    __shared__ float img_s[784];
    __shared__ float w_s[64 * 81];
    __shared__ ushort xsH[32][408];
    __shared__ ushort xsL[32][408];
    for (int idx = t; idx < 784; idx += 256) img_s[idx] = img[b * 784 + idx];
    for (int idx = t; idx < 64 * 81; idx += 256) w_s[idx] = w[ct * 64 * 81 + idx];
    __syncthreads();
#pragma unroll
    for (int ph = 0; ph < 2; ++ph) {
        if (ph) __syncthreads();
        for (int task = t; task < 640; task += 256) {
            const int cl2 = task / 20;
            const int cl  = ph * 32 + cl2;
            const int oy  = task - cl2 * 20;
            float acc[20];
            const float bv = bias[ct * 64 + cl];
#pragma unroll
            for (int j = 0; j < 20; ++j) acc[j] = bv;
#pragma unroll
            for (int ky = 0; ky < 9; ++ky) {
                float rowv[28];
                const float* r = &img_s[(oy + ky) * 28];
#pragma unroll
                for (int j = 0; j < 28; ++j) rowv[j] = r[j];
#pragma unroll
                for (int kx = 0; kx < 9; ++kx) {
                    const float wv = w_s[cl * 81 + ky * 9 + kx];
#pragma unroll
                    for (int j = 0; j < 20; ++j) acc[j] += wv * rowv[j + kx];
                }
            }
#pragma unroll
            for (int j = 0; j < 20; ++j) {
                ushort hb, lb;
                split_bf16(fmaxf(acc[j], 0.f), hb, lb);
                xsH[cl2][oy * 20 + j] = hb;
                xsL[cl2][oy * 20 + j] = lb;
            }
        }
        __syncthreads();
        for (int u2 = t; u2 < 1600; u2 += 256) {
            const int c = u2 / 400;
            const int p = u2 - c * 400;
            ushort8v vh, vl;
#pragma unroll
            for (int j = 0; j < 8; ++j) {
                vh[j] = xsH[c * 8 + j][p];
                vl[j] = xsL[c * 8 + j][p];
            }
            const int cc = ct * 8 + ph * 4 + c;
            const size_t o = (((size_t)b * 32 + cc) * 400 + p) * 8;
            *(ushort8v*)(xTh + o) = vh;
            *(ushort8v*)(xTl + o) = vl;
        }
    }
}

// ------------------------------ wsplit3 ------------------------------------
__global__ __launch_bounds__(256) void wsplit3_kernel(
    const float* __restrict__ pw, ushort* __restrict__ Wfh, ushort* __restrict__ Wfl)
{
    const int oc = blockIdx.x & 255;
    const int qg = blockIdx.x >> 8;
    const int t  = threadIdx.x;
    __shared__ float buf[5184];
    const float* row = pw + (size_t)oc * 20736 + qg * 5184;
    for (int idx = t; idx < 5184; idx += 256) buf[idx] = row[idx];
    __syncthreads();
    for (int task = t; task < 656; task += 256) {
        const int qcl = task / 82;
        const int tt  = task - qcl * 82;
        const int T   = tt >> 1;
        const int hh  = tt & 1;
        const int tap = 2 * T + hh;
        const int qc  = qg * 8 + qcl;
        ushort8v h8, l8;
#pragma unroll
        for (int j = 0; j < 8; ++j) {
            const float v = (tap <= 80) ? buf[qcl * 648 + j * 81 + tap] : 0.f;
            ushort hb, lb;
            split_bf16(v, hb, lb);
            h8[j] = hb; l8[j] = lb;
        }
        const size_t rec = (((size_t)(qc * 41 + T) * 256 + oc) * 2 + hh) * 8;
        *(ushort8v*)(Wfh + rec) = h8;
        *(ushort8v*)(Wfl + rec) = l8;
    }
}

// ------------------------------- gemm10 ------------------------------------
__global__ __launch_bounds__(256, 3) void gemm10_kernel(
    const ushort* __restrict__ xTh, const ushort* __restrict__ xTl,
    const ushort* __restrict__ Wfh, const ushort* __restrict__ Wfl,
    float* __restrict__ part)
{
    const int bid = blockIdx.x;          // 576
    const int q = bid & 7, mt = bid >> 3;
    const int t = threadIdx.x;           // 0..255
    const int w = t >> 6, lane = t & 63; // w = og (0..3)
    const int ln = lane & 31, h = lane >> 5;

    __shared__ ushort As[20480];

    const int m_base = mt * 64;
    const int bmin = m_base / 36;

    uint soff[5];
#pragma unroll
    for (int r = 0; r < 5; ++r) {
        int j = t + r * 256;
        if (j >= 1200) j = 0;
        const int rbj = j / 400;
        const int gp  = sigr(j) - rbj * 400;
        soff[r] = (uint)((bmin + rbj) * 204800 + q * 25600 + gp * 16);
    }

    int pb0, pb1;
    {
        int m = m_base + ln;
        int b = m / 36, pos = m - b * 36;
        pb0 = (b - bmin) * 400 + (pos / 6) * 40 + (pos % 6) * 2;
        m += 32;
        b = m / 36; pos = m - b * 36;
        pb1 = (b - bmin) * 400 + (pos / 6) * 40 + (pos % 6) * 2;
    }

    const uint wlane = (uint)((w * 64 + ln) * 16 + h * 8);

    f32x16 acc00, acc01, acc10, acc11;
#pragma unroll
    for (int i = 0; i < 16; ++i) { acc00[i] = 0.f; acc01[i] = 0.f; acc10[i] = 0.f; acc11[i] = 0.f; }

#define G10_OFF(T_, s0_, s1_)                                                  \
    {                                                                          \
        const int tap_ = 2 * (T_) + h;                                         \
        const int ky_  = (tap_ * 57) >> 9;                                     \
        const int off_ = ky_ * 20 + tap_ - 9 * ky_;                            \
        s0_ = sigr(pb0 + off_);                                                \
        s1_ = sigr(pb1 + off_);                                                \
    }

#define G10_LOAD(T_, a0h_, a0l_, a1h_, a1l_, w0h_, w1h_, w0l_, w1l_)           \
    {                                                                          \
        int s0_, s1_;                                                          \
        G10_OFF(T_, s0_, s1_)                                                  \
        a0h_ = *(const short8*)(As + s0_ * 8);                                 \
        a0l_ = *(const short8*)(As + (1280 + s0_) * 8);                        \
        a1h_ = *(const short8*)(As + s1_ * 8);                                 \
        a1l_ = *(const short8*)(As + (1280 + s1_) * 8);                        \
        const ushort* wh_ = wbh + (size_t)(T_) * 4096;                         \
        const ushort* wl_ = wbl + (size_t)(T_) * 4096;                         \
        w0h_ = *(const short8*)(wh_);                                          \
        w1h_ = *(const short8*)(wh_ + 512);                                    \
        w0l_ = *(const short8*)(wl_);                                          \
        w1l_ = *(const short8*)(wl_ + 512);                                    \
    }

#define G10_MFMA(a0h_, a0l_, a1h_, a1l_, w0h_, w1h_, w0l_, w1l_)               \
    {                                                                          \
        acc00 = MFMA32(a0h_, w0h_, acc00);                                     \
        acc00 = MFMA32(a0l_, w0h_, acc00);                                     \
        acc00 = MFMA32(a0h_, w0l_, acc00);                                     \
        acc01 = MFMA32(a0h_, w1h_, acc01);                                     \
        acc01 = MFMA32(a0l_, w1h_, acc01);                                     \
        acc01 = MFMA32(a0h_, w1l_, acc01);                                     \
        acc10 = MFMA32(a1h_, w0h_, acc10);                                     \
        acc10 = MFMA32(a1l_, w0h_, acc10);                                     \
        acc10 = MFMA32(a1h_, w0l_, acc10);                                     \
        acc11 = MFMA32(a1h_, w1h_, acc11);                                     \
        acc11 = MFMA32(a1l_, w1h_, acc11);                                     \
        acc11 = MFMA32(a1h_, w1l_, acc11);                                     \
    }

#define G10_STAGE(c_)                                                          \
    {                                                                          \
        const uint cc = (uint)(c_) * 6400u;                                    \
        _Pragma("unroll")                                                      \
        for (int r = 0; r < 5; ++r) {                                          \
            if (r < 4 || t < 176) {                                            \
                gl_lds16((const char*)xTh + soff[r] + cc,                      \
                         (char*)As + (r * 256 + w * 64) * 16);                 \
                gl_lds16((const char*)xTl + soff[r] + cc,                      \
                         (char*)As + 20480 + (r * 256 + w * 64) * 16);         \
            }                                                                  \
        }                                                                      \
    }

    for (int c = 0; c < 4; ++c) {
        if (c > 0) __syncthreads();
        G10_STAGE(c);
        __syncthreads();                // implicit vmcnt(0): stage visible

        const ushort* wbh = Wfh + (size_t)(q * 4 + c) * 41 * 4096 + wlane;
        const ushort* wbl = Wfl + (size_t)(q * 4 + c) * 41 * 4096 + wlane;

        short8 A0h, A0l, A1h, A1l, W0h, W1h, W0l, W1l;   // set0
        short8 B0h, B0l, B1h, B1l, V0h, V1h, V0l, V1l;   // set1
        G10_LOAD(0, A0h, A0l, A1h, A1l, W0h, W1h, W0l, W1l)
        G10_LOAD(1, B0h, B0l, B1h, B1l, V0h, V1h, V0l, V1l)

#pragma unroll 1
        for (int TT = 0; TT < 40; TT += 2) {
            G10_MFMA(A0h, A0l, A1h, A1l, W0h, W1h, W0l, W1l)        // T = TT
            {
                const int Tn = (TT + 2 <= 40) ? TT + 2 : 40;
                G10_LOAD(Tn, A0h, A0l, A1h, A1l, W0h, W1h, W0l, W1l)
            }
            G10_MFMA(B0h, B0l, B1h, B1l, V0h, V1h, V0l, V1l)        // T = TT+1
            {
                const int Tn = (TT + 3 <= 40) ? TT + 3 : 40;
                G10_LOAD(Tn, B0h, B0l, B1h, B1l, V0h, V1h, V0l, V1l)
            }
        }
        G10_MFMA(A0h, A0l, A1h, A1l, W0h, W1h, W0l, W1l)            // T = 40
    }
#undef G10_STAGE
#undef G10_MFMA
#undef G10_LOAD
#undef G10_OFF

    float* pq = part + (size_t)q * 1179648;
#pragma unroll
    for (int mf = 0; mf < 2; ++mf) {
#pragma unroll
        for (int nf = 0; nf < 2; ++nf) {
            const f32x16 a = (mf == 0) ? (nf == 0 ? acc00 : acc01)
                                       : (nf == 0 ? acc10 : acc11);
            const int oc = w * 64 + nf * 32 + ln;
            float* pb = pq + (oc >> 3) * 288 + (oc & 7);
#pragma unroll
            for (int r = 0; r < 16; ++r) {
                const int m = m_base + mf * 32 + (r & 3) + 8 * (r >> 2) + 4 * h;
                const int b = m / 36;
                const int pos = m - b * 36;
                pb[(size_t)b * 9216 + pos * 8] = a[r];
            }
        }
    }
}

// ------------------------------- squash ------------------------------------
__global__ __launch_bounds__(256) void squash_kernel(
    const float* __restrict__ part, const float* __restrict__ bias,
    float* __restrict__ u, int nq)
{
    const int idx = blockIdx.x * 256 + threadIdx.x;
    if (idx >= 128 * 1152) return;
    const int i   = idx % 1152;
    const int cap = i / 36;
    float4 s0, s1;
    {
        const float* bv = bias + cap * 8;
        s0 = make_float4(bv[0], bv[1], bv[2], bv[3]);
        s1 = make_float4(bv[4], bv[5], bv[6], bv[7]);
    }
    for (int qq = 0; qq < nq; ++qq) {
        const float4* p = (const float4*)(part + (size_t)qq * 1179648 + (size_t)idx * 8);
        const float4 a = p[0], b4 = p[1];
        s0.x += a.x; s0.y += a.y; s0.z += a.z; s0.w += a.w;
        s1.x += b4.x; s1.y += b4.y; s1.z += b4.z; s1.w += b4.w;
    }
    const float n2 = s0.x*s0.x + s0.y*s0.y + s0.z*s0.z + s0.w*s0.w
                   + s1.x*s1.x + s1.y*s1.y + s1.z*s1.z + s1.w*s1.w;
    const float sc = sqrtf(n2) / (1.f + n2);
    *(float4*)(u + (size_t)idx * 8)     = make_float4(s0.x*sc, s0.y*sc, s0.z*sc, s0.w*sc);
    *(float4*)(u + (size_t)idx * 8 + 4) = make_float4(s1.x*sc, s1.y*sc, s1.z*sc, s1.w*sc);
}

// ------------------------------- uhat --------------------------------------
__device__ __forceinline__ float4 uhat4(const float* __restrict__ urow,
                                        const float* __restrict__ wrow)
{
    float ur[8];
    const float4 u0 = *(const float4*)urow;
    const float4 u1 = *(const float4*)(urow + 4);
    ur[0] = u0.x; ur[1] = u0.y; ur[2] = u0.z; ur[3] = u0.w;
    ur[4] = u1.x; ur[5] = u1.y; ur[6] = u1.z; ur[7] = u1.w;
    float4 uh = make_float4(0.f, 0.f, 0.f, 0.f);
#pragma unroll
    for (int c = 0; c < 8; ++c) {
        const float4 wv = *(const float4*)(wrow + c * 16);
        uh.x += ur[c] * wv.x; uh.y += ur[c] * wv.y;
        uh.z += ur[c] * wv.z; uh.w += ur[c] * wv.w;
    }
    return uh;
}

__global__ __launch_bounds__(256) void uhat_kernel(
    const float* __restrict__ u, const float* __restrict__ rw,
    ushort* __restrict__ uh)
{
    const int i0 = blockIdx.x * 16;
    const int o  = blockIdx.y;
    const int t  = threadIdx.x;
    __shared__ float rs[2048];
    const float* rsl = rw + ((size_t)o * 1152 + i0) * 128;
    for (int idx = t; idx < 2048; idx += 256) rs[idx] = rsl[idx];
    __syncthreads();
    const int dq = t & 3, il = (t >> 2) & 15, b0 = t >> 6;
    for (int b = b0; b < 128; b += 4) {
        const float4 v = uhat4(u + ((size_t)b * 1152 + i0 + il) * 8,
                               &rs[il * 128 + dq * 4]);
        __hip_bfloat16 q0 = __float2bfloat16(v.x);
        __hip_bfloat16 q1 = __float2bfloat16(v.y);
        __hip_bfloat16 q2 = __float2bfloat16(v.z);
        __hip_bfloat16 q3 = __float2bfloat16(v.w);
        ushort4 hb;
        hb.x = *(ushort*)&q0; hb.y = *(ushort*)&q1;
        hb.z = *(ushort*)&q2; hb.w = *(ushort*)&q3;
        *(ushort4*)(uh + (((size_t)b * 10 + o) * 1152 + i0 + il) * 16 + dq * 4) = hb;
    }
}

// ------------------------------- routing v3 --------------------------------
__device__ __forceinline__ float4 uh_from_lds(const ushort* uhs, int i, int d4)
{
    const uint2 rv = *(const uint2*)(uhs + i * 16 + d4);
    float4 r;
    r.x = __uint_as_float((rv.x & 0xffffu) << 16);
    r.y = __uint_as_float((rv.x >> 16) << 16);
    r.z = __uint_as_float((rv.y & 0xffffu) << 16);
    r.w = __uint_as_float((rv.y >> 16) << 16);
    return r;
}

__global__ __launch_bounds__(256) void routing_kernel(
    const ushort* __restrict__ uh_g, float* __restrict__ out)
{
    const int b = blockIdx.x;
    const int o = blockIdx.y;
    const int t = threadIdx.x;
    __shared__ ushort uh_s[1152 * 16];
    __shared__ float logits[1152];
    __shared__ float ebuf[1152];
    __shared__ float psum[64][17];
    __shared__ float red[8];
    __shared__ float v_s[16];
    const ushort8v* src = (const ushort8v*)(uh_g + ((size_t)b * 10 + o) * 18432);
    for (int idx = t; idx < 2304; idx += 256) ((ushort8v*)uh_s)[idx] = src[idx];
    for (int i = t; i < 1152; i += 256) logits[i] = 0.f;
    __syncthreads();
    const int dq = t & 3;
    const int ig = t >> 2;
    const int d4 = dq * 4;
    for (int iter = 1; iter <= 3; ++iter) {
        float lmax = -3.0e38f;
        for (int i = t; i < 1152; i += 256) lmax = fmaxf(lmax, logits[i]);
#pragma unroll
        for (int off = 32; off; off >>= 1) lmax = fmaxf(lmax, __shfl_xor(lmax, off, 64));
        if ((t & 63) == 0) red[t >> 6] = lmax;
        __syncthreads();
        const float m = fmaxf(fmaxf(red[0], red[1]), fmaxf(red[2], red[3]));
        float ls = 0.f;
        for (int i = t; i < 1152; i += 256) {
            const float e = expf(logits[i] - m);
            ebuf[i] = e;
            ls += e;
        }
#pragma unroll
        for (int off = 32; off; off >>= 1) ls += __shfl_xor(ls, off, 64);
        if ((t & 63) == 0) red[4 + (t >> 6)] = ls;
        __syncthreads();
        const float sumE = red[4] + red[5] + red[6] + red[7];
        float4 ps = make_float4(0.f, 0.f, 0.f, 0.f);
        for (int i = ig; i < 1152; i += 64) {
            const float4 uhv = uh_from_lds(uh_s, i, d4);
            const float e = ebuf[i];
            ps.x += e * uhv.x; ps.y += e * uhv.y; ps.z += e * uhv.z; ps.w += e * uhv.w;
        }
        psum[ig][d4 + 0] = ps.x; psum[ig][d4 + 1] = ps.y;
        psum[ig][d4 + 2] = ps.z; psum[ig][d4 + 3] = ps.w;
        __syncthreads();
        if (t < 16) {
            float s = 0.f;
            for (int g = 0; g < 64; ++g) s += psum[g][t];
            s /= sumE;
            float qn = s * s;
            qn += __shfl_xor(qn, 1, 16); qn += __shfl_xor(qn, 2, 16);
            qn += __shfl_xor(qn, 4, 16); qn += __shfl_xor(qn, 8, 16);
            v_s[t] = s * sqrtf(qn) / (1.f + qn);
        }
        __syncthreads();
        if (iter < 3) {
            const float v0 = v_s[d4 + 0], v1 = v_s[d4 + 1];
            const float v2 = v_s[d4 + 2], v3 = v_s[d4 + 3];
            for (int i = ig; i < 1152; i += 64) {
                const float4 uhv = uh_from_lds(uh_s, i, d4);
                float pr = uhv.x * v0 + uhv.y * v1 + uhv.z * v2 + uhv.w * v3;
                pr += __shfl_xor(pr, 1, 64);
                pr += __shfl_xor(pr, 2, 64);
                if (dq == 0) logits[i] += pr;
            }
            __syncthreads();
        }
    }
    if (t < 16) out[((size_t)b * 10 + o) * 16 + t] = v_s[t];
}

// ===================== FALLBACK (R5 fp32 direct conv) ======================
#define WSL4 1344

__global__ __launch_bounds__(256) void conv1_kernel(
    const float* __restrict__ img, const float* __restrict__ w,
    const float* __restrict__ bias, float* __restrict__ x)
{
    const int ct = blockIdx.x;
    const int b  = blockIdx.y;
    const int t  = threadIdx.x;
    __shared__ float img_s[784];
    __shared__ float w_s[64 * 81];
    for (int idx = t; idx < 784; idx += 256) img_s[idx] = img[b * 784 + idx];
    for (int idx = t; idx < 64 * 81; idx += 256) w_s[idx] = w[ct * 64 * 81 + idx];
    __syncthreads();
    for (int task = t; task < 1280; task += 256) {
        const int cl = task / 20;
        const int oy = task - cl * 20;
        float acc[20];
        const float bv = bias[ct * 64 + cl];
#pragma unroll
        for (int j = 0; j < 20; ++j) acc[j] = bv;
#pragma unroll
        for (int ky = 0; ky < 9; ++ky) {
            float rowv[28];
            const float* r = &img_s[(oy + ky) * 28];
#pragma unroll
            for (int j = 0; j < 28; ++j) rowv[j] = r[j];
#pragma unroll
            for (int kx = 0; kx < 9; ++kx) {
                const float wv = w_s[cl * 81 + ky * 9 + kx];
#pragma unroll
                for (int j = 0; j < 20; ++j) acc[j] += wv * rowv[j + kx];
            }
        }
        float* xp = x + (((size_t)b * 256 + ct * 64 + cl) * 400) + oy * 20;
#pragma unroll
        for (int j = 0; j < 20; ++j) xp[j] = fmaxf(acc[j], 0.f);
    }
}

__global__ __launch_bounds__(256) void wtrans_kernel(
    const float* __restrict__ w, float* __restrict__ wT)
{
    const int idx = blockIdx.x * 256 + threadIdx.x;
    if (idx >= 4 * 256 * 81 * 16) return;
    const int c      = idx & 15;
    const int k      = (idx >> 4) % 81;
    const int ic     = ((idx >> 4) / 81) % 256;
    const int octile = idx / (16 * 81 * 256);
    const int ocb    = octile * 64 + c * 4;
    float4 v;
    v.x = w[((size_t)(ocb + 0) * 256 + ic) * 81 + k];
    v.y = w[((size_t)(ocb + 1) * 256 + ic) * 81 + k];
    v.z = w[((size_t)(ocb + 2) * 256 + ic) * 81 + k];
    v.w = w[((size_t)(ocb + 3) * 256 + ic) * 81 + k];
    ((float4*)wT)[((size_t)octile * 256 + ic) * WSL4 + k * 16 + c] = v;
}

__global__ __launch_bounds__(384) void pcaps_kernel(
    const float* __restrict__ x, const float* __restrict__ wT,
    float* __restrict__ part)
{
    const int btile  = blockIdx.x;
    const int octile = blockIdx.y;
    const int ict    = blockIdx.z;
    const int t    = threadIdx.x;
    const int wave = t >> 6;
    const int lane = t & 63;
    __shared__ float4 w_s[2][WSL4];
    __shared__ float4 x_s[2][448];
    const int oc4  = (t & 15) * 4;
    const int slot = t >> 4;
    const int bb   = slot / 6;
    const int oy   = slot - 6 * bb;
    const int b0   = btile * 4;
    float acc[6][4];
#pragma unroll
    for (int p = 0; p < 6; ++p) {
        acc[p][0] = 0.f; acc[p][1] = 0.f; acc[p][2] = 0.f; acc[p][3] = 0.f;
    }
    const float*  xg   = x + (size_t)b0 * 102400 + (size_t)ict * 25600;
    const float4* wsrc = (const float4*)wT + ((size_t)octile * 256 + ict * 64) * WSL4;
#define PCAPS_STAGE(bf_, ic_)                                                  \
    {                                                                          \
        const float4* gsl = wsrc + (size_t)(ic_) * WSL4;                       \
        for (int ch = wave; ch < 21; ch += 6)                                  \
            gl_lds16(gsl + ch * 64 + lane, &w_s[bf_][ch * 64]);                \
        for (int ch = wave; ch < 7; ch += 6) {                                 \
            int idx = ch * 64 + lane;                                          \
            if (idx >= 400) idx = 0;                                           \
            const int xbb = idx / 100;                                         \
            const int off = idx - xbb * 100;                                   \
            const float* g = xg + (size_t)xbb * 102400 + (ic_) * 400 + off * 4;\
            gl_lds16(g, &x_s[bf_][ch * 64]);                                   \
        }                                                                      \
    }
    PCAPS_STAGE(0, 0);
    __syncthreads();
    int buf = 0;
    for (int ic = 0; ic < 64; ++ic) {
        if (ic < 63) PCAPS_STAGE(buf ^ 1, ic + 1);
        const float* xrow = (const float*)x_s[buf] + bb * 400;
        const float* wrow = (const float*)w_s[buf];
#pragma unroll
        for (int ky = 0; ky < 9; ++ky) {
            float rowv[20];
            const float4* xr = (const float4*)&xrow[(2 * oy + ky) * 20];
#pragma unroll
            for (int j = 0; j < 5; ++j) ((float4*)rowv)[j] = xr[j];
#pragma unroll
            for (int kx = 0; kx < 9; ++kx) {
                const float4 wv = *(const float4*)&wrow[(ky * 9 + kx) * 64 + oc4];
#pragma unroll
                for (int p = 0; p < 6; ++p) {
                    const float xv = rowv[2 * p + kx];
                    acc[p][0] += xv * wv.x; acc[p][1] += xv * wv.y;
                    acc[p][2] += xv * wv.z; acc[p][3] += xv * wv.w;
                }
            }
        }
        __syncthreads();
        buf ^= 1;
    }
#undef PCAPS_STAGE
    float* pb = part + ((size_t)ict * 128 + (b0 + bb)) * 9216;
    const int oc0 = octile * 64 + oc4;
    const int cap = oc0 >> 3;
    const int d0  = oc0 & 7;
#pragma unroll
    for (int p = 0; p < 6; ++p) {
        const int pos = oy * 6 + p;
        *(float4*)&pb[((size_t)cap * 36 + pos) * 8 + d0] =
            make_float4(acc[p][0], acc[p][1], acc[p][2], acc[p][3]);
    }
}

__global__ __launch_bounds__(256) void squash_fb_kernel(
    const float* __restrict__ part, const float* __restrict__ bias,
    float* __restrict__ u, int nq)
{
    const int idx = blockIdx.x * 256 + threadIdx.x;
    if (idx >= 128 * 1152) return;
    const int i   = idx % 1152;
    const int cap = i / 36;
    float v[8];
    float n2 = 0.f;
#pragma unroll
    for (int c = 0; c < 8; ++c) {
        float s = bias[cap * 8 + c];
        for (int qq = 0; qq < nq; ++qq) s += part[(size_t)qq * 1179648 + (size_t)idx * 8 + c];
        v[c] = s;
        n2 += s * s;
    }
    const float sc = sqrtf(n2) / (1.f + n2);
#pragma unroll
    for (int c = 0; c < 8; ++c) u[(size_t)idx * 8 + c] = v[c] * sc;
}

__global__ __launch_bounds__(256) void routing_fb_kernel(
    const float* __restrict__ u, const float* __restrict__ rw,
    float* __restrict__ out)
{
    const int b = blockIdx.x;
    const int o = blockIdx.y;
    const int t = threadIdx.x;
    __shared__ ushort uh_s[1152 * 16];
    __shared__ float logits[1152];
    __shared__ float ebuf[1152];
    __shared__ float psum[64][17];
    __shared__ float red[8];
    __shared__ float v_s[16];
    const float* ub = u + (size_t)b * 9216;
    const float* wo = rw + (size_t)o * 147456;
    for (int i = t; i < 1152; i += 256) logits[i] = 0.f;
    __syncthreads();
    const int dq = t & 3;
    const int ig = t >> 2;
    const int d4 = dq * 4;
    for (int iter = 1; iter <= 3; ++iter) {
        float lmax = -3.0e38f;
        for (int i = t; i < 1152; i += 256) lmax = fmaxf(lmax, logits[i]);
#pragma unroll
        for (int off = 32; off; off >>= 1) lmax = fmaxf(lmax, __shfl_xor(lmax, off, 64));
        if ((t & 63) == 0) red[t >> 6] = lmax;
        __syncthreads();
        const float m = fmaxf(fmaxf(red[0], red[1]), fmaxf(red[2], red[3]));
        float ls = 0.f;
        for (int i = t; i < 1152; i += 256) {
            const float e = expf(logits[i] - m);
            ebuf[i] = e;
            ls += e;
        }
#pragma unroll
        for (int off = 32; off; off >>= 1) ls += __shfl_xor(ls, off, 64);
        if ((t & 63) == 0) red[4 + (t >> 6)] = ls;
        __syncthreads();
        const float sumE = red[4] + red[5] + red[6] + red[7];
        float4 ps = make_float4(0.f, 0.f, 0.f, 0.f);
        if (iter == 1) {
            for (int i = ig; i < 1152; i += 64) {
                const float4 uhv = uhat4(ub + i * 8, wo + (size_t)i * 128 + d4);
                __hip_bfloat16 q0 = __float2bfloat16(uhv.x);
                __hip_bfloat16 q1 = __float2bfloat16(uhv.y);
                __hip_bfloat16 q2 = __float2bfloat16(uhv.z);
                __hip_bfloat16 q3 = __float2bfloat16(uhv.w);
                ushort4 hb;
                hb.x = *(ushort*)&q0; hb.y = *(ushort*)&q1;
                hb.z = *(ushort*)&q2; hb.w = *(ushort*)&q3;
                *(ushort4*)(uh_s + i * 16 + d4) = hb;
                const float e = ebuf[i];
                ps.x += e * uhv.x; ps.y += e * uhv.y; ps.z += e * uhv.z; ps.w += e * uhv.w;
            }
        } else {
            for (int i = ig; i < 1152; i += 64) {
                const float4 uhv = uh_from_lds(uh_s, i, d4);
                const float e = ebuf[i];
                ps.x += e * uhv.x; ps.y += e * uhv.y; ps.z += e * uhv.z; ps.w += e * uhv.w;
            }
        }
        psum[ig][d4 + 0] = ps.x; psum[ig][d4 + 1] = ps.y;
        psum[ig][d4 + 2] = ps.z; psum[ig][d4 + 3] = ps.w;
        __syncthreads();
        if (t < 16) {
            float s = 0.f;
            for (int g = 0; g < 64; ++g) s += psum[g][t];
            s /= sumE;
            float qn = s * s;
            qn += __shfl_xor(qn, 1, 16); qn += __shfl_xor(qn, 2, 16);
            qn += __shfl_xor(qn, 4, 16); qn += __shfl_xor(qn, 8, 16);
            v_s[t] = s * sqrtf(qn) / (1.f + qn);
        }
        __syncthreads();
        if (iter < 3) {
            const float v0 = v_s[d4 + 0], v1 = v_s[d4 + 1];
            const float v2 = v_s[d4 + 2], v3 = v_s[d4 + 3];
            for (int i = ig; i < 1152; i += 64) {
                const float4 uhv = uh_from_lds(uh_s, i, d4);
                float pr = uhv.x * v0 + uhv.y * v1 + uhv.z * v2 + uhv.w * v3;
                pr += __shfl_xor(pr, 1, 64);
                pr += __shfl_xor(pr, 2, 64);
                if (dq == 0) logits[i] += pr;
            }
            __syncthreads();
        }
    }
    if (t < 16) out[((size_t)b * 10 + o) * 16 + t] = v_s[t];
}

// ------------------------------- launcher ----------------------------------
extern "C" void kernel_launch(void* const* d_in, const int* in_sizes, int n_in,
                              void* d_out, int out_size, void* d_ws, size_t ws_size,
                              hipStream_t stream)
{
    const float* img = (const float*)d_in[0];
    const float* c1w = (const float*)d_in[1];
    const float* c1b = (const float*)d_in[2];
    const float* pw  = (const float*)d_in[3];
    const float* pb  = (const float*)d_in[4];
    const float* rw  = (const float*)d_in[5];
    float* out = (float*)d_out;
    char* ws = (char*)d_ws;

    if (ws_size >= 116391936ULL) {
        // fast path (116,391,936 B)
        ushort* xTh  = (ushort*)(ws);                  // dead after gemm10
        ushort* xTl  = (ushort*)(ws + 26214400);       // dead after gemm10
        ushort* uh   = (ushort*)(ws);                  // aliases dead xT
        ushort* Wfh  = (ushort*)(ws + 52428800);
        ushort* Wfl  = (ushort*)(ws + 63176704);
        float*  part = (float*)(ws + 73924608);
        float*  u    = (float*)(ws + 111673344);
        hipLaunchKernelGGL(conv1c_kernel, dim3(4, 128), dim3(256), 0, stream, img, c1w, c1b, xTh, xTl);
        hipLaunchKernelGGL(wsplit3_kernel, dim3(1024), dim3(256), 0, stream, pw, Wfh, Wfl);
        hipLaunchKernelGGL(gemm10_kernel, dim3(576), dim3(256), 0, stream, xTh, xTl, Wfh, Wfl, part);
        hipLaunchKernelGGL(squash_kernel, dim3(576), dim3(256), 0, stream, part, pb, u, 8);
        hipLaunchKernelGGL(uhat_kernel, dim3(72, 10), dim3(256), 0, stream, u, rw, uh);
        hipLaunchKernelGGL(routing_kernel, dim3(128, 10), dim3(256), 0, stream, uh, out);
    } else {
        // fallback: R5 fp32 direct conv (97.9 MB, proven)
        float* x    = (float*)(ws);
        float* part = (float*)(ws + 52428800);
        float* u    = (float*)(ws + 52428800 + 18874368);
        float* wT   = (float*)(ws + 52428800 + 18874368 + 4718592);
        hipLaunchKernelGGL(wtrans_kernel, dim3((4 * 256 * 81 * 16 + 255) / 256), dim3(256), 0, stream, pw, wT);
        hipLaunchKernelGGL(conv1_kernel, dim3(4, 128), dim3(256), 0, stream, img, c1w, c1b, x);
        hipLaunchKernelGGL(pcaps_kernel, dim3(32, 4, 4), dim3(384), 0, stream, x, wT, part);
        hipLaunchKernelGGL(squash_fb_kernel, dim3(576), dim3(256), 0, stream, part, pb, u, 4);
        hipLaunchKernelGGL(routing_fb_kernel, dim3(128, 10), dim3(256), 0, stream, u, rw, out);
    }
}